// Round 3
// baseline (652.963 us; speedup 1.0000x reference)
//
#include <hip/hip_runtime.h>

#define NB 32768
#define NF 256
#define H1 16
#define H2 8
#define R_PER_BLOCK 64
#define CHUNK 16
#define NT 256          // one thread per feature

__device__ __forceinline__ float elu_f(float v) {
    return v > 0.0f ? v : (__expf(v) - 1.0f);
}

// One thread per feature, ALL params in true VGPRs (~220 live -> 256-bin,
// 2 waves/SIMD, no AGPR spill churn). Dual-row (R=2) register blocking gives
// two independent dep chains per thread so exp/load latency of one row hides
// under the FMAs of the other.
__global__ __launch_bounds__(NT, 2)
void nul_kernel(const float* __restrict__ x,
                const float* __restrict__ W1, const float* __restrict__ b1,
                const float* __restrict__ W2, const float* __restrict__ b2,
                const float* __restrict__ W3, const float* __restrict__ b3,
                const float* __restrict__ theta, const float* __restrict__ bias,
                float* __restrict__ y_out, float* __restrict__ w_out,
                float* __restrict__ z_out) {
    const int f = threadIdx.x;              // feature
    const int rowBase = blockIdx.x * R_PER_BLOCK;

    // ---- per-feature params -> registers (float4 loads) ----
    float w1v[H1], b1v[H1], w2v[H1 * H2], b2v[H2], w3v[H2];
    {
        const float4* p = reinterpret_cast<const float4*>(W1 + f * H1);
        #pragma unroll
        for (int i = 0; i < H1 / 4; ++i) {
            float4 v = p[i];
            w1v[4*i] = v.x; w1v[4*i+1] = v.y; w1v[4*i+2] = v.z; w1v[4*i+3] = v.w;
        }
    }
    {
        const float4* p = reinterpret_cast<const float4*>(b1 + f * H1);
        #pragma unroll
        for (int i = 0; i < H1 / 4; ++i) {
            float4 v = p[i];
            b1v[4*i] = v.x; b1v[4*i+1] = v.y; b1v[4*i+2] = v.z; b1v[4*i+3] = v.w;
        }
    }
    {
        const float4* p = reinterpret_cast<const float4*>(W2 + f * H1 * H2);
        #pragma unroll
        for (int i = 0; i < (H1 * H2) / 4; ++i) {
            float4 v = p[i];
            w2v[4*i] = v.x; w2v[4*i+1] = v.y; w2v[4*i+2] = v.z; w2v[4*i+3] = v.w;
        }
    }
    {
        const float4* p = reinterpret_cast<const float4*>(b2 + f * H2);
        #pragma unroll
        for (int i = 0; i < H2 / 4; ++i) {
            float4 v = p[i];
            b2v[4*i] = v.x; b2v[4*i+1] = v.y; b2v[4*i+2] = v.z; b2v[4*i+3] = v.w;
        }
    }
    {
        const float4* p = reinterpret_cast<const float4*>(W3 + f * H2);
        #pragma unroll
        for (int i = 0; i < H2 / 4; ++i) {
            float4 v = p[i];
            w3v[4*i] = v.x; w3v[4*i+1] = v.y; w3v[4*i+2] = v.z; w3v[4*i+3] = v.w;
        }
    }
    const float b3v   = b3[f];
    const float th    = theta[f];
    const float wv    = logf(1.0f + __expf(th));   // softplus
    const float biasv = bias[0];

    if (blockIdx.x == 0) w_out[f] = wv;            // weights output once

    __shared__ float P[CHUNK][NF + 1];             // +1 pad vs bank conflicts

    const float* xp = x + rowBase * NF + f;        // this thread's x column

    // rolling prefetch: two rows ahead
    float xa = xp[0];
    float xb = xp[NF];

    for (int c = 0; c < R_PER_BLOCK; c += CHUNK) {
        #pragma unroll 1
        for (int r = 0; r < CHUNK; r += 2) {
            const int row0 = rowBase + c + r;

            // prefetch the next row pair (clamped inside the block; clamped
            // values are only fetched, never consumed)
            int p0 = c + r + 2; if (p0 > R_PER_BLOCK - 1) p0 = R_PER_BLOCK - 1;
            int p1 = c + r + 3; if (p1 > R_PER_BLOCK - 1) p1 = R_PER_BLOCK - 1;
            const float xa2 = xp[p0 * NF];
            const float xb2 = xp[p1 * NF];

            // ---- layers 1+2 for both rows, interleaved ----
            float acc0[H2], acc1[H2];
            #pragma unroll
            for (int k = 0; k < H2; ++k) { acc0[k] = b2v[k]; acc1[k] = b2v[k]; }
            #pragma unroll
            for (int h = 0; h < H1; ++h) {
                const float ha = elu_f(fmaf(xa, w1v[h], b1v[h]));
                const float hb = elu_f(fmaf(xb, w1v[h], b1v[h]));
                #pragma unroll
                for (int k = 0; k < H2; ++k) {
                    const float w = w2v[h * H2 + k];
                    acc0[k] = fmaf(ha, w, acc0[k]);
                    acc1[k] = fmaf(hb, w, acc1[k]);
                }
            }

            // ---- layer 3 for both rows ----
            float z0 = b3v, z1 = b3v;
            #pragma unroll
            for (int k = 0; k < H2; ++k) {
                z0 = fmaf(elu_f(acc0[k]), w3v[k], z0);
                z1 = fmaf(elu_f(acc1[k]), w3v[k], z1);
            }

            z_out[row0 * NF + f]       = z0;       // coalesced Z writes
            z_out[(row0 + 1) * NF + f] = z1;
            P[r][f]     = wv * z0;                 // stage for y reduction
            P[r + 1][f] = wv * z1;

            xa = xa2; xb = xb2;
        }
        __syncthreads();
        {
            // 16 rows x 256 partials, 16 threads per row
            const int rr = threadIdx.x >> 4;       // row within chunk
            const int l  = threadIdx.x & 15;
            float s = 0.0f;
            #pragma unroll
            for (int i = 0; i < 16; ++i) s += P[rr][i * 16 + l];
            #pragma unroll
            for (int o = 8; o > 0; o >>= 1) s += __shfl_down(s, o, 16);
            if (l == 0) y_out[rowBase + c + rr] = s + biasv;
        }
        __syncthreads();
    }
}

extern "C" void kernel_launch(void* const* d_in, const int* in_sizes, int n_in,
                              void* d_out, int out_size, void* d_ws, size_t ws_size,
                              hipStream_t stream) {
    const float* x     = (const float*)d_in[0];
    const float* W1    = (const float*)d_in[1];
    const float* b1    = (const float*)d_in[2];
    const float* W2    = (const float*)d_in[3];
    const float* b2    = (const float*)d_in[4];
    const float* W3    = (const float*)d_in[5];
    const float* b3    = (const float*)d_in[6];
    const float* theta = (const float*)d_in[7];
    const float* bias  = (const float*)d_in[8];

    float* y_out = (float*)d_out;                  // [32768]
    float* w_out = y_out + NB;                     // [256]
    float* z_out = w_out + NF;                     // [32768*256]

    nul_kernel<<<NB / R_PER_BLOCK, NT, 0, stream>>>(
        x, W1, b1, W2, b2, W3, b3, theta, bias, y_out, w_out, z_out);
}

// Round 6
// 162.375 us; speedup vs baseline: 4.0213x; 4.0213x over previous
//
#include <hip/hip_runtime.h>

#define NB 32768
#define NF 256
#define H1 16
#define H2 8
#define ROWS_PER_BLOCK 1024
#define ITERS (ROWS_PER_BLOCK / 64)   // 16
#define FPB 4                         // features (waves) per block
#define NT (FPB * 64)                 // 256 threads

__device__ __forceinline__ float elu_f(float v) {
    return v > 0.0f ? v : (__expf(v) - 1.0f);
}
// force a wave-uniform float into an SGPR
__device__ __forceinline__ float rfl(float v) {
    return __int_as_float(__builtin_amdgcn_readfirstlane(__float_as_int(v)));
}

// One WAVE per feature; lanes = 64 consecutive rows. All params wave-uniform:
// W2 rows 0..7 + b1 in SGPRs (readfirstlane), rest as uniform VGPR copies.
// No LDS, no barriers, no shuffles, no AGPRs in the hot loop.
__global__ __launch_bounds__(NT, 4)
void z_kernel(const float* __restrict__ x,  const float* __restrict__ W1,
              const float* __restrict__ b1, const float* __restrict__ W2,
              const float* __restrict__ b2, const float* __restrict__ W3,
              const float* __restrict__ b3, float* __restrict__ z_out) {
    const int wave = threadIdx.x >> 6;
    const int lane = threadIdx.x & 63;
    const int f    = blockIdx.y * FPB + wave;
    const int rowBase = blockIdx.x * ROWS_PER_BLOCK;

    // ---- W2: rows 0..7 -> SGPR, rows 8..15 -> uniform VGPR copies ----
    float s_w2[8 * H2];      // SGPRs via readfirstlane
    float w2h[8 * H2];       // VGPRs
    {
        const float4* p = reinterpret_cast<const float4*>(W2 + f * H1 * H2);
        #pragma unroll
        for (int i = 0; i < 16; ++i) {
            float4 v = p[i];
            s_w2[4*i]   = rfl(v.x); s_w2[4*i+1] = rfl(v.y);
            s_w2[4*i+2] = rfl(v.z); s_w2[4*i+3] = rfl(v.w);
        }
        #pragma unroll
        for (int i = 0; i < 16; ++i) {
            float4 v = p[16 + i];
            w2h[4*i] = v.x; w2h[4*i+1] = v.y; w2h[4*i+2] = v.z; w2h[4*i+3] = v.w;
        }
    }
    // ---- W1 -> VGPR, b1 -> SGPR (fma takes 1 SGPR operand: fmaf(x, w1, s_b1)) ----
    float w1v[H1], s_b1[H1];
    {
        const float4* pw = reinterpret_cast<const float4*>(W1 + f * H1);
        const float4* pb = reinterpret_cast<const float4*>(b1 + f * H1);
        #pragma unroll
        for (int i = 0; i < 4; ++i) {
            float4 v = pw[i];
            w1v[4*i] = v.x; w1v[4*i+1] = v.y; w1v[4*i+2] = v.z; w1v[4*i+3] = v.w;
        }
        #pragma unroll
        for (int i = 0; i < 4; ++i) {
            float4 v = pb[i];
            s_b1[4*i]   = rfl(v.x); s_b1[4*i+1] = rfl(v.y);
            s_b1[4*i+2] = rfl(v.z); s_b1[4*i+3] = rfl(v.w);
        }
    }
    float b2v[H2], w3v[H2];
    {
        const float4* p = reinterpret_cast<const float4*>(b2 + f * H2);
        float4 v0 = p[0], v1 = p[1];
        b2v[0]=v0.x; b2v[1]=v0.y; b2v[2]=v0.z; b2v[3]=v0.w;
        b2v[4]=v1.x; b2v[5]=v1.y; b2v[6]=v1.z; b2v[7]=v1.w;
    }
    {
        const float4* p = reinterpret_cast<const float4*>(W3 + f * H2);
        float4 v0 = p[0], v1 = p[1];
        w3v[0]=v0.x; w3v[1]=v0.y; w3v[2]=v0.z; w3v[3]=v0.w;
        w3v[4]=v1.x; w3v[5]=v1.y; w3v[6]=v1.z; w3v[7]=v1.w;
    }
    const float b3v = b3[f];

    // x and z share the same [row][feature] layout -> one rolling offset
    int off = (rowBase + lane) * NF + f;
    float xv = x[off];

    #pragma unroll 1
    for (int it = 0; it < ITERS; ++it) {
        const int noff = off + 64 * NF;
        const float xn = x[(it + 1 < ITERS) ? noff : off];   // prefetch next 64-row slab

        float acc[H2];
        #pragma unroll
        for (int k = 0; k < H2; ++k) acc[k] = b2v[k];

        #pragma unroll
        for (int h = 0; h < 8; ++h) {                        // W2 rows 0..7 from SGPR
            const float h1 = elu_f(fmaf(xv, w1v[h], s_b1[h]));
            #pragma unroll
            for (int k = 0; k < H2; ++k)
                acc[k] = fmaf(h1, s_w2[h * H2 + k], acc[k]);
        }
        #pragma unroll
        for (int h = 0; h < 8; ++h) {                        // W2 rows 8..15 from VGPR
            const float h1 = elu_f(fmaf(xv, w1v[8 + h], s_b1[8 + h]));
            #pragma unroll
            for (int k = 0; k < H2; ++k)
                acc[k] = fmaf(h1, w2h[h * H2 + k], acc[k]);
        }

        float z = b3v;
        #pragma unroll
        for (int k = 0; k < H2; ++k)
            z = fmaf(elu_f(acc[k]), w3v[k], z);

        z_out[off] = z;
        off = noff; xv = xn;
    }
}

// Memory-bound epilogue: w = softplus(theta); y[row] = dot(z[row,:], w) + bias.
#define NT2 256
#define ROWS2 64
__global__ __launch_bounds__(NT2, 4)
void y_kernel(const float* __restrict__ z, const float* __restrict__ theta,
              const float* __restrict__ bias, float* __restrict__ y_out,
              float* __restrict__ w_out) {
    __shared__ __align__(16) float wls[NF];
    const int tid = threadIdx.x;
    {
        const float th = theta[tid];
        const float w  = logf(1.0f + __expf(th));
        wls[tid] = w;
        if (blockIdx.x == 0) w_out[tid] = w;
    }
    __syncthreads();
    const int wave = tid >> 6, lane = tid & 63;
    const float4 w4 = reinterpret_cast<const float4*>(wls)[lane];
    const float biasv = bias[0];
    #pragma unroll 1
    for (int r = 0; r < ROWS2 / 4; ++r) {          // 16 rows per wave
        const int row = blockIdx.x * ROWS2 + wave * (ROWS2 / 4) + r;
        const float4 zv = reinterpret_cast<const float4*>(z + row * NF)[lane];
        float s = zv.x * w4.x + zv.y * w4.y + zv.z * w4.z + zv.w * w4.w;
        #pragma unroll
        for (int o = 32; o > 0; o >>= 1) s += __shfl_down(s, o, 64);
        if (lane == 0) y_out[row] = s + biasv;
    }
}

extern "C" void kernel_launch(void* const* d_in, const int* in_sizes, int n_in,
                              void* d_out, int out_size, void* d_ws, size_t ws_size,
                              hipStream_t stream) {
    const float* x     = (const float*)d_in[0];
    const float* W1    = (const float*)d_in[1];
    const float* b1    = (const float*)d_in[2];
    const float* W2    = (const float*)d_in[3];
    const float* b2    = (const float*)d_in[4];
    const float* W3    = (const float*)d_in[5];
    const float* b3    = (const float*)d_in[6];
    const float* theta = (const float*)d_in[7];
    const float* bias  = (const float*)d_in[8];

    float* y_out = (float*)d_out;                  // [32768]
    float* w_out = y_out + NB;                     // [256]
    float* z_out = w_out + NF;                     // [32768*256]

    dim3 grid1(NB / ROWS_PER_BLOCK, NF / FPB);     // 32 x 64
    z_kernel<<<grid1, NT, 0, stream>>>(x, W1, b1, W2, b2, W3, b3, z_out);
    y_kernel<<<NB / ROWS2, NT2, 0, stream>>>(z_out, theta, bias, y_out, w_out);
}